// Round 11
// baseline (306.300 us; speedup 1.0000x reference)
//
#include <hip/hip_runtime.h>
#include <hip/hip_bf16.h>
#include <cstdint>
#include <cstddef>

typedef __bf16 bf16;
typedef __bf16 bf16x4 __attribute__((ext_vector_type(4)));
typedef __bf16 bf16x8 __attribute__((ext_vector_type(8)));
typedef float f32x4 __attribute__((ext_vector_type(4)));

#define NB 4
#define NS 2048
#define ND 1024
#define NH 16
#define NHD 64
#define NM (NB * NS)  // 8192

// 0.125 * log2(e): folded into Q at qkv epilogue so attn can use raw v_exp_f32
#define QSCALE 0.18033688011112042f

// async global->LDS, 16B per lane; LDS dest = wave-uniform base + lane*16
__device__ inline void lds_dma16(const bf16* g, bf16* l) {
    __builtin_amdgcn_global_load_lds(
        (const __attribute__((address_space(1))) void*)g,
        (__attribute__((address_space(3))) void*)l, 16, 0, 0);
}

// ---------------------------------------------------------------------------
// Fused prep: RoPE table + bf16(hs) + bf16(Wqkv) [+ bf16(Wo) when ws allows].
// ---------------------------------------------------------------------------
#define NHS4 2097152   // NM*ND/4
#define NWQ4 786432    // 3*ND*ND/4
#define NWO4 262144    // ND*ND/4
__global__ void prep_kernel(const float4* __restrict__ hs, const float4* __restrict__ wq,
                            const float4* __restrict__ wo,
                            float* __restrict__ cost, float* __restrict__ sint,
                            bf16x4* __restrict__ X, bf16x4* __restrict__ Wb,
                            bf16x4* __restrict__ Wob) {
    int i = blockIdx.x * 256 + threadIdx.x;
    if (i < NS * 32) {
        int s = i >> 5, f = i & 31;
        float inv = exp2f(-(float)f * (13.287712379549449f / 32.0f));
        float ang = (float)s * inv;
        cost[i] = cosf(ang);
        sint[i] = sinf(ang);
    }
    if (i < NHS4) {
        float4 v = hs[i];
        bf16x4 r = {(bf16)v.x, (bf16)v.y, (bf16)v.z, (bf16)v.w};
        X[i] = r;
    } else if (i < NHS4 + NWQ4) {
        int j = i - NHS4;
        float4 v = wq[j];
        bf16x4 r = {(bf16)v.x, (bf16)v.y, (bf16)v.z, (bf16)v.w};
        Wb[j] = r;
    } else {  // only reached when grid extended (fused-Wo path)
        int j = i - NHS4 - NWQ4;
        float4 v = wo[j];
        bf16x4 r = {(bf16)v.x, (bf16)v.y, (bf16)v.z, (bf16)v.w};
        Wob[j] = r;
    }
}

// fp32 -> bf16 bulk convert — fallback for Wo when ws too small for Wob region.
__global__ void cvt_bf16_kernel(const float4* __restrict__ in, bf16x4* __restrict__ out) {
    int i = blockIdx.x * 256 + threadIdx.x;
    float4 v = in[i];
    bf16x4 r = {(bf16)v.x, (bf16)v.y, (bf16)v.z, (bf16)v.w};
    out[i] = r;
}

// ---------------------------------------------------------------------------
// QKV GEMM v5 (r7 measured best: 77.5us, MfmaUtil 27%, 0 bank conflicts):
// single-buffer 2-barrier loop, BK=64, XOR-swizzled LDS.
// ---------------------------------------------------------------------------
__global__ void __launch_bounds__(256) qkv_rope_gemm(
    const bf16* __restrict__ A, const bf16* __restrict__ W,
    const float* __restrict__ bias,
    const float* __restrict__ cost, const float* __restrict__ sint,
    bf16* __restrict__ Qw, bf16* __restrict__ Kw, bf16* __restrict__ Vt) {
    __shared__ __attribute__((aligned(16))) bf16 lA[128 * 64];
    __shared__ __attribute__((aligned(16))) bf16 lB[128 * 64];

    int t = threadIdx.x, lane = t & 63, w = t >> 6;
    int col = lane & 15, quad = lane >> 4;
    int m0 = blockIdx.y * 128, n0 = blockIdx.x * 128;
    int wm = (w >> 1) * 64, wn = (w & 1) * 64;

    f32x4 acc[4][4];
#pragma unroll
    for (int i = 0; i < 4; ++i)
#pragma unroll
        for (int j = 0; j < 4; ++j) acc[i][j] = (f32x4){0.f, 0.f, 0.f, 0.f};

    int srow = t >> 3;
    int sslot = (t & 7) ^ (srow & 7);
    const bf16* gA = A + (size_t)(m0 + srow) * ND + sslot * 8;
    const bf16* gB = W + (size_t)(n0 + srow) * ND + sslot * 8;

    int aRow = (wm + col) * 64;
    int bRow = (wn + col) * 64;

    for (int kt = 0; kt < 16; ++kt) {
        int kc = kt * 64;
#pragma unroll
        for (int c = 0; c < 4; ++c) {
            lds_dma16(gA + (size_t)(c * 32) * ND + kc, &lA[c * 2048 + t * 8]);
            lds_dma16(gB + (size_t)(c * 32) * ND + kc, &lB[c * 2048 + t * 8]);
        }
        __syncthreads();
#pragma unroll
        for (int kh = 0; kh < 2; ++kh) {
            int sk = ((kh * 4 + quad) ^ (col & 7)) * 8;
            bf16x8 af[4], bg[4];
#pragma unroll
            for (int i = 0; i < 4; ++i)
                af[i] = *(const bf16x8*)&lA[aRow + i * 1024 + sk];
#pragma unroll
            for (int j = 0; j < 4; ++j)
                bg[j] = *(const bf16x8*)&lB[bRow + j * 1024 + sk];
#pragma unroll
            for (int i = 0; i < 4; ++i)
#pragma unroll
                for (int j = 0; j < 4; ++j)
                    acc[i][j] = __builtin_amdgcn_mfma_f32_16x16x32_bf16(af[i], bg[j], acc[i][j], 0, 0, 0);
        }
        __syncthreads();
    }

    // Epilogue. Wave's 64 n-cols lie in one (which, head) segment.
    int nseg = n0 + wn;
    int which = nseg >> 10;
    int h = (nseg >> 6) & (NH - 1);
    float bj[4];
#pragma unroll
    for (int j = 0; j < 4; ++j) bj[j] = bias[nseg + j * 16 + col];

    if (which == 2) {
        int mbase = m0 + wm;            // 64-aligned; never crosses a b-boundary
        int b = mbase >> 11;
        bf16* dsth = Vt + (size_t)(b * NH + h) * NHD * NS;
#pragma unroll
        for (int i = 0; i < 4; ++i) {
            int s = ((mbase + i * 16) & (NS - 1)) + quad * 4;
#pragma unroll
            for (int j = 0; j < 4; ++j) {
                bf16x4 pv = {(bf16)(acc[i][j][0] + bj[j]), (bf16)(acc[i][j][1] + bj[j]),
                             (bf16)(acc[i][j][2] + bj[j]), (bf16)(acc[i][j][3] + bj[j])};
                *(bf16x4*)(dsth + (size_t)(j * 16 + col) * NS + s) = pv;
            }
        }
    } else {
        float sc = which ? 1.0f : QSCALE;  // fold softmax scale*log2e into Q
#pragma unroll
        for (int i = 0; i < 4; ++i) {
#pragma unroll
            for (int r = 0; r < 4; ++r) {
                int m = m0 + wm + i * 16 + quad * 4 + r;
                int b = m >> 11, s = m & (NS - 1);
                float v0 = acc[i][0][r] + bj[0];
                float v1 = acc[i][1][r] + bj[1];
                float v2 = acc[i][2][r] + bj[2];
                float v3 = acc[i][3][r] + bj[3];
                bf16* dst = (which ? Kw : Qw) + ((size_t)(b * NH + h) * NS + s) * NHD;
                float c0 = cost[s * 32 + col], s0 = sint[s * 32 + col];
                float c1 = cost[s * 32 + 16 + col], s1 = sint[s * 32 + 16 + col];
                dst[col] = (bf16)((v0 * c0 - v2 * s0) * sc);
                dst[16 + col] = (bf16)((v1 * c1 - v3 * s1) * sc);
                dst[32 + col] = (bf16)((v0 * s0 + v2 * c0) * sc);
                dst[48 + col] = (bf16)((v1 * s1 + v3 * c1) * sc);
            }
        }
    }
}

// ---------------------------------------------------------------------------
// Flash attention v11: 4 waves, 128-q-row block, 2-way KEY-SPLIT, grid 1024
// (= 4 blocks/CU; v8's 512-block grid capped occupancy at 2 waves/SIMD).
//   - wave w: q-rows (w>>1)*64 (mb=4, v8's full LDS amortization), key half
//     ks=(w&1)*32 of a 64-key tile (v10-verified split math + end reduction)
//   - K/V staged via global_load_lds + r7-proven XOR swizzle (zero staging
//     registers; qkv's exact 0-conflict read pattern); single-buffer 16KB,
//     2-barrier loop (qkv r7 structure)
//   - denom via VALU pairwise sums + 2 end shfls (replaces ones-MFMA dacc:
//     -12 regs, v6-verified reduce) -> ~120 regs; lb(256,3) caps at 170
//     (no v10 spill mode possible), natural alloc can reach 4 blocks/CU
// ---------------------------------------------------------------------------
__global__ void __launch_bounds__(256, 3) attn_kernel(
    const bf16* __restrict__ Qw, const bf16* __restrict__ Kw,
    const bf16* __restrict__ Vt, bf16* __restrict__ X) {
    // K tile [64 keys][64 d], V tile [64 hd][64 keys]; both linear, cols
    // XOR-swizzled in 16B slots: LDS[row][s*8+j] = G[row][(s^(row&7))*8+j]
    __shared__ __attribute__((aligned(16))) bf16 smem[8192];  // 16KB
    bf16* lK = smem;          // 4096
    bf16* lV = smem + 4096;   // 4096

    int t = threadIdx.x, lane = t & 63, w = t >> 6;   // w 0..3
    int col = lane & 15, q = lane >> 4;
    int bh = blockIdx.y, b = bh >> 4, h = bh & 15;
    int ks = (w & 1) * 32;                  // key half within 64-key tile
    int q0 = blockIdx.x * 128 + (w >> 1) * 64;
    const bf16* Qh = Qw + (size_t)bh * NS * NHD;
    const bf16* Kh = Kw + (size_t)bh * NS * NHD;
    const bf16* Vh = Vt + (size_t)bh * NHD * NS;

    // staging sources (pre-swizzled cols): thread t covers chunks t and t+256
    // chunk c: row c>>3, slot c&7; (t+256)>>3 = r+32, same &7 -> same swizzle
    int sr = t >> 3;
    int sc8 = ((t & 7) ^ (sr & 7)) * 8;
    const bf16* gK = Kh + (size_t)sr * NHD + sc8;
    const bf16* gV = Vh + (size_t)sr * NS + sc8;

    bf16x8 bQ[4][2];
#pragma unroll
    for (int mb = 0; mb < 4; ++mb)
#pragma unroll
        for (int h2 = 0; h2 < 2; ++h2)
            bQ[mb][h2] = *(const bf16x8*)(Qh + (size_t)(q0 + mb * 16 + col) * NHD + h2 * 32 + q * 8);

    f32x4 o[4][4];
#pragma unroll
    for (int mb = 0; mb < 4; ++mb)
#pragma unroll
        for (int hb = 0; hb < 4; ++hb) o[mb][hb] = (f32x4){0.f, 0.f, 0.f, 0.f};
    float dsum[4] = {0.f, 0.f, 0.f, 0.f};

    // fragment read offsets (swizzled)
    int vu0 = (ks >> 3) + (q >> 1);         // V 16B-unit for lo half
    int vhalf = (q & 1) << 2;               // 8B half within unit

    for (int kt = 0; kt < 32; ++kt) {
        // stage 64-key tile: K 8KB + V 8KB, 2 chunks/thread/matrix
        lds_dma16(gK + (size_t)(kt * 64) * NHD, &lK[w * 512]);
        lds_dma16(gK + (size_t)(kt * 64 + 32) * NHD, &lK[2048 + w * 512]);
        lds_dma16(gV + kt * 64, &lV[w * 512]);
        lds_dma16(gV + kt * 64 + (size_t)32 * NS, &lV[2048 + w * 512]);
        __syncthreads();

        bf16x8 aK[2][2];
#pragma unroll
        for (int tb = 0; tb < 2; ++tb) {
            int row = ks + tb * 16 + col;
#pragma unroll
            for (int h2 = 0; h2 < 2; ++h2) {
                int u = h2 * 4 + q;
                aK[tb][h2] = *(const bf16x8*)&lK[row * 64 + ((u ^ (row & 7)) << 3)];
            }
        }
        bf16x8 vf[4];
#pragma unroll
        for (int hb = 0; hb < 4; ++hb) {
            int row = hb * 16 + col;
            bf16x4 lo = *(const bf16x4*)&lV[row * 64 + ((vu0 ^ (row & 7)) << 3) + vhalf];
            bf16x4 hi = *(const bf16x4*)&lV[row * 64 + (((vu0 + 2) ^ (row & 7)) << 3) + vhalf];
            vf[hb] = __builtin_shufflevector(lo, hi, 0, 1, 2, 3, 4, 5, 6, 7);
        }
        __builtin_amdgcn_s_setprio(1);
#pragma unroll
        for (int mb = 0; mb < 4; ++mb) {
            f32x4 s0 = (f32x4){0.f, 0.f, 0.f, 0.f};
            f32x4 s1 = (f32x4){0.f, 0.f, 0.f, 0.f};
            s0 = __builtin_amdgcn_mfma_f32_16x16x32_bf16(aK[0][0], bQ[mb][0], s0, 0, 0, 0);
            s0 = __builtin_amdgcn_mfma_f32_16x16x32_bf16(aK[0][1], bQ[mb][1], s0, 0, 0, 0);
            s1 = __builtin_amdgcn_mfma_f32_16x16x32_bf16(aK[1][0], bQ[mb][0], s1, 0, 0, 0);
            s1 = __builtin_amdgcn_mfma_f32_16x16x32_bf16(aK[1][1], bQ[mb][1], s1, 0, 0, 0);
            bf16x8 pf;
            float dsa = 0.f, dsb = 0.f;
#pragma unroll
            for (int r = 0; r < 4; ++r) {
                float p0 = __builtin_amdgcn_exp2f(s0[r]);
                float p1 = __builtin_amdgcn_exp2f(s1[r]);
                pf[r] = (bf16)p0;
                pf[4 + r] = (bf16)p1;
                dsa += p0;
                dsb += p1;
            }
            dsum[mb] += dsa + dsb;
#pragma unroll
            for (int hb = 0; hb < 4; ++hb)
                o[mb][hb] = __builtin_amdgcn_mfma_f32_16x16x32_bf16(vf[hb], pf, o[mb][hb], 0, 0, 0);
        }
        __builtin_amdgcn_s_setprio(0);
        __syncthreads();
    }

    // quad-reduce dsum (each lane summed only its 8 keys of the 32)
#pragma unroll
    for (int mb = 0; mb < 4; ++mb) {
        dsum[mb] += __shfl_xor(dsum[mb], 16);
        dsum[mb] += __shfl_xor(dsum[mb], 32);
    }

    // cross-pair reduction: (w, w^1) share q-rows, differ in key half.
    // Scratch overlays the dead K/V tiles: 128 lanes x 17 f32 = 8.7KB < 16KB.
    float* rsc = (float*)smem;
#pragma unroll
    for (int mb = 0; mb < 4; ++mb) {
        __syncthreads();
        float* sc = rsc + ((w >> 1) * 64 + lane) * 17;
        if (w & 1) {
#pragma unroll
            for (int hb = 0; hb < 4; ++hb)
#pragma unroll
                for (int r = 0; r < 4; ++r) sc[hb * 4 + r] = o[mb][hb][r];
            sc[16] = dsum[mb];
        }
        __syncthreads();
        if (!(w & 1)) {
            float linv = 1.0f / (dsum[mb] + sc[16]);
            int s = q0 + mb * 16 + col;
            bf16* dst = X + (size_t)(b * NS + s) * ND + h * NHD;
#pragma unroll
            for (int hb = 0; hb < 4; ++hb) {
                bf16x4 ov = {(bf16)((o[mb][hb][0] + sc[hb * 4 + 0]) * linv),
                             (bf16)((o[mb][hb][1] + sc[hb * 4 + 1]) * linv),
                             (bf16)((o[mb][hb][2] + sc[hb * 4 + 2]) * linv),
                             (bf16)((o[mb][hb][3] + sc[hb * 4 + 3]) * linv)};
                *(bf16x4*)(dst + hb * 16 + q * 4) = ov;
            }
        }
    }
}

// ---------------------------------------------------------------------------
// Output projection v5 (r7 measured best): BK=64 single-buffer swizzled loop.
// ---------------------------------------------------------------------------
__global__ void __launch_bounds__(256) out_gemm(
    const bf16* __restrict__ A, const bf16* __restrict__ W,
    const float* __restrict__ bias, float* __restrict__ out) {
    __shared__ __attribute__((aligned(16))) bf16 lA[128 * 64];
    __shared__ __attribute__((aligned(16))) bf16 lB[128 * 64];

    int t = threadIdx.x, lane = t & 63, w = t >> 6;
    int col = lane & 15, quad = lane >> 4;
    int m0 = blockIdx.y * 128, n0 = blockIdx.x * 128;
    int wm = (w >> 1) * 64, wn = (w & 1) * 64;

    f32x4 acc[4][4];
#pragma unroll
    for (int i = 0; i < 4; ++i)
#pragma unroll
        for (int j = 0; j < 4; ++j) acc[i][j] = (f32x4){0.f, 0.f, 0.f, 0.f};

    int srow = t >> 3;
    int sslot = (t & 7) ^ (srow & 7);
    const bf16* gA = A + (size_t)(m0 + srow) * ND + sslot * 8;
    const bf16* gB = W + (size_t)(n0 + srow) * ND + sslot * 8;
    int aRow = (wm + col) * 64;
    int bRow = (wn + col) * 64;

    for (int kt = 0; kt < 16; ++kt) {
        int kc = kt * 64;
#pragma unroll
        for (int c = 0; c < 4; ++c) {
            lds_dma16(gA + (size_t)(c * 32) * ND + kc, &lA[c * 2048 + t * 8]);
            lds_dma16(gB + (size_t)(c * 32) * ND + kc, &lB[c * 2048 + t * 8]);
        }
        __syncthreads();
#pragma unroll
        for (int kh = 0; kh < 2; ++kh) {
            int sk = ((kh * 4 + quad) ^ (col & 7)) * 8;
            bf16x8 af[4], bg[4];
#pragma unroll
            for (int i = 0; i < 4; ++i)
                af[i] = *(const bf16x8*)&lA[aRow + i * 1024 + sk];
#pragma unroll
            for (int j = 0; j < 4; ++j)
                bg[j] = *(const bf16x8*)&lB[bRow + j * 1024 + sk];
#pragma unroll
            for (int i = 0; i < 4; ++i)
#pragma unroll
                for (int j = 0; j < 4; ++j)
                    acc[i][j] = __builtin_amdgcn_mfma_f32_16x16x32_bf16(af[i], bg[j], acc[i][j], 0, 0, 0);
        }
        __syncthreads();
    }

    float bj[4];
#pragma unroll
    for (int j = 0; j < 4; ++j) bj[j] = bias[n0 + wn + j * 16 + col];
#pragma unroll
    for (int i = 0; i < 4; ++i)
#pragma unroll
        for (int r = 0; r < 4; ++r) {
            int m = m0 + wm + i * 16 + quad * 4 + r;
#pragma unroll
            for (int j = 0; j < 4; ++j)
                out[(size_t)m * ND + n0 + wn + j * 16 + col] = acc[i][j][r] + bj[j];
        }
}

// ---------------------------------------------------------------------------
// ws layout: cos|sin (512K) | Qw 16M | Kw 16M | Vt 16M | X 16M [| Wo_b 2M]
// ---------------------------------------------------------------------------
extern "C" void kernel_launch(void* const* d_in, const int* in_sizes, int n_in,
                              void* d_out, int out_size, void* d_ws, size_t ws_size,
                              hipStream_t stream) {
    const float* hs = (const float*)d_in[0];
    const float* Wqkv = (const float*)d_in[1];
    const float* bqkv = (const float*)d_in[2];
    const float* Wo = (const float*)d_in[3];
    const float* bo = (const float*)d_in[4];
    float* out = (float*)d_out;

    char* ws = (char*)d_ws;
    float* cost = (float*)ws;
    float* sint = cost + NS * 32;
    bf16* Qw = (bf16*)(ws + 524288);
    bf16* Kw = Qw + (size_t)NB * NH * NS * NHD;
    bf16* Vt = Kw + (size_t)NB * NH * NS * NHD;
    bf16* X = Vt + (size_t)NB * NH * NS * NHD;
    bf16* Wqkv_b = (bf16*)d_out;   // scratch inside d_out, dead before out_gemm

    const size_t base_end = 524288 + (size_t)4 * NB * NH * NS * NHD * 2;  // 64.5MB
    bool fuse_wo = ws_size >= base_end + (size_t)ND * ND * 2;
    bf16* Wo_b = fuse_wo ? (bf16*)(ws + base_end) : Qw;  // Qw dead after attn

    int prep_blocks = (NHS4 + NWQ4 + (fuse_wo ? NWO4 : 0)) / 256;
    prep_kernel<<<dim3(prep_blocks), dim3(256), 0, stream>>>(
        (const float4*)hs, (const float4*)Wqkv, (const float4*)Wo,
        cost, sint, (bf16x4*)X, (bf16x4*)Wqkv_b, (bf16x4*)Wo_b);
    qkv_rope_gemm<<<dim3(3 * ND / 128, NM / 128), dim3(256), 0, stream>>>(
        X, Wqkv_b, bqkv, cost, sint, Qw, Kw, Vt);
    attn_kernel<<<dim3(NS / 128, NB * NH), dim3(256), 0, stream>>>(Qw, Kw, Vt, X);
    if (!fuse_wo)
        cvt_bf16_kernel<<<dim3(ND * ND / 4 / 256), dim3(256), 0, stream>>>(
            (const float4*)Wo, (bf16x4*)Wo_b);
    out_gemm<<<dim3(ND / 128, NM / 128), dim3(256), 0, stream>>>(X, Wo_b, bo, out);
}

// Round 12
// 255.370 us; speedup vs baseline: 1.1994x; 1.1994x over previous
//
#include <hip/hip_runtime.h>
#include <hip/hip_bf16.h>
#include <cstdint>
#include <cstddef>

typedef __bf16 bf16;
typedef __bf16 bf16x4 __attribute__((ext_vector_type(4)));
typedef __bf16 bf16x8 __attribute__((ext_vector_type(8)));
typedef float f32x4 __attribute__((ext_vector_type(4)));

#define NB 4
#define NS 2048
#define ND 1024
#define NH 16
#define NHD 64
#define NM (NB * NS)  // 8192

// 0.125 * log2(e): folded into Q at qkv epilogue so attn can use raw v_exp_f32
#define QSCALE 0.18033688011112042f

// async global->LDS, 16B per lane; LDS dest = wave-uniform base + lane*16
__device__ inline void lds_dma16(const bf16* g, bf16* l) {
    __builtin_amdgcn_global_load_lds(
        (const __attribute__((address_space(1))) void*)g,
        (__attribute__((address_space(3))) void*)l, 16, 0, 0);
}

// ---------------------------------------------------------------------------
// Fused prep: RoPE table + bf16(hs) + bf16(Wqkv) [+ bf16(Wo) when ws allows].
// ---------------------------------------------------------------------------
#define NHS4 2097152   // NM*ND/4
#define NWQ4 786432    // 3*ND*ND/4
#define NWO4 262144    // ND*ND/4
__global__ void prep_kernel(const float4* __restrict__ hs, const float4* __restrict__ wq,
                            const float4* __restrict__ wo,
                            float* __restrict__ cost, float* __restrict__ sint,
                            bf16x4* __restrict__ X, bf16x4* __restrict__ Wb,
                            bf16x4* __restrict__ Wob) {
    int i = blockIdx.x * 256 + threadIdx.x;
    if (i < NS * 32) {
        int s = i >> 5, f = i & 31;
        float inv = exp2f(-(float)f * (13.287712379549449f / 32.0f));
        float ang = (float)s * inv;
        cost[i] = cosf(ang);
        sint[i] = sinf(ang);
    }
    if (i < NHS4) {
        float4 v = hs[i];
        bf16x4 r = {(bf16)v.x, (bf16)v.y, (bf16)v.z, (bf16)v.w};
        X[i] = r;
    } else if (i < NHS4 + NWQ4) {
        int j = i - NHS4;
        float4 v = wq[j];
        bf16x4 r = {(bf16)v.x, (bf16)v.y, (bf16)v.z, (bf16)v.w};
        Wb[j] = r;
    } else {  // only reached when grid extended (fused-Wo path)
        int j = i - NHS4 - NWQ4;
        float4 v = wo[j];
        bf16x4 r = {(bf16)v.x, (bf16)v.y, (bf16)v.z, (bf16)v.w};
        Wob[j] = r;
    }
}

// fp32 -> bf16 bulk convert — fallback for Wo when ws too small for Wob region.
__global__ void cvt_bf16_kernel(const float4* __restrict__ in, bf16x4* __restrict__ out) {
    int i = blockIdx.x * 256 + threadIdx.x;
    float4 v = in[i];
    bf16x4 r = {(bf16)v.x, (bf16)v.y, (bf16)v.z, (bf16)v.w};
    out[i] = r;
}

// ---------------------------------------------------------------------------
// QKV GEMM v5 (r7 measured best: 77.5us, MfmaUtil 27%, 0 bank conflicts):
// single-buffer 2-barrier loop, BK=64, XOR-swizzled LDS.
// ---------------------------------------------------------------------------
__global__ void __launch_bounds__(256) qkv_rope_gemm(
    const bf16* __restrict__ A, const bf16* __restrict__ W,
    const float* __restrict__ bias,
    const float* __restrict__ cost, const float* __restrict__ sint,
    bf16* __restrict__ Qw, bf16* __restrict__ Kw, bf16* __restrict__ Vt) {
    __shared__ __attribute__((aligned(16))) bf16 lA[128 * 64];
    __shared__ __attribute__((aligned(16))) bf16 lB[128 * 64];

    int t = threadIdx.x, lane = t & 63, w = t >> 6;
    int col = lane & 15, quad = lane >> 4;
    int m0 = blockIdx.y * 128, n0 = blockIdx.x * 128;
    int wm = (w >> 1) * 64, wn = (w & 1) * 64;

    f32x4 acc[4][4];
#pragma unroll
    for (int i = 0; i < 4; ++i)
#pragma unroll
        for (int j = 0; j < 4; ++j) acc[i][j] = (f32x4){0.f, 0.f, 0.f, 0.f};

    int srow = t >> 3;
    int sslot = (t & 7) ^ (srow & 7);
    const bf16* gA = A + (size_t)(m0 + srow) * ND + sslot * 8;
    const bf16* gB = W + (size_t)(n0 + srow) * ND + sslot * 8;

    int aRow = (wm + col) * 64;
    int bRow = (wn + col) * 64;

    for (int kt = 0; kt < 16; ++kt) {
        int kc = kt * 64;
#pragma unroll
        for (int c = 0; c < 4; ++c) {
            lds_dma16(gA + (size_t)(c * 32) * ND + kc, &lA[c * 2048 + t * 8]);
            lds_dma16(gB + (size_t)(c * 32) * ND + kc, &lB[c * 2048 + t * 8]);
        }
        __syncthreads();
#pragma unroll
        for (int kh = 0; kh < 2; ++kh) {
            int sk = ((kh * 4 + quad) ^ (col & 7)) * 8;
            bf16x8 af[4], bg[4];
#pragma unroll
            for (int i = 0; i < 4; ++i)
                af[i] = *(const bf16x8*)&lA[aRow + i * 1024 + sk];
#pragma unroll
            for (int j = 0; j < 4; ++j)
                bg[j] = *(const bf16x8*)&lB[bRow + j * 1024 + sk];
#pragma unroll
            for (int i = 0; i < 4; ++i)
#pragma unroll
                for (int j = 0; j < 4; ++j)
                    acc[i][j] = __builtin_amdgcn_mfma_f32_16x16x32_bf16(af[i], bg[j], acc[i][j], 0, 0, 0);
        }
        __syncthreads();
    }

    // Epilogue. Wave's 64 n-cols lie in one (which, head) segment.
    int nseg = n0 + wn;
    int which = nseg >> 10;
    int h = (nseg >> 6) & (NH - 1);
    float bj[4];
#pragma unroll
    for (int j = 0; j < 4; ++j) bj[j] = bias[nseg + j * 16 + col];

    if (which == 2) {
        int mbase = m0 + wm;            // 64-aligned; never crosses a b-boundary
        int b = mbase >> 11;
        bf16* dsth = Vt + (size_t)(b * NH + h) * NHD * NS;
#pragma unroll
        for (int i = 0; i < 4; ++i) {
            int s = ((mbase + i * 16) & (NS - 1)) + quad * 4;
#pragma unroll
            for (int j = 0; j < 4; ++j) {
                bf16x4 pv = {(bf16)(acc[i][j][0] + bj[j]), (bf16)(acc[i][j][1] + bj[j]),
                             (bf16)(acc[i][j][2] + bj[j]), (bf16)(acc[i][j][3] + bj[j])};
                *(bf16x4*)(dsth + (size_t)(j * 16 + col) * NS + s) = pv;
            }
        }
    } else {
        float sc = which ? 1.0f : QSCALE;  // fold softmax scale*log2e into Q
#pragma unroll
        for (int i = 0; i < 4; ++i) {
#pragma unroll
            for (int r = 0; r < 4; ++r) {
                int m = m0 + wm + i * 16 + quad * 4 + r;
                int b = m >> 11, s = m & (NS - 1);
                float v0 = acc[i][0][r] + bj[0];
                float v1 = acc[i][1][r] + bj[1];
                float v2 = acc[i][2][r] + bj[2];
                float v3 = acc[i][3][r] + bj[3];
                bf16* dst = (which ? Kw : Qw) + ((size_t)(b * NH + h) * NS + s) * NHD;
                float c0 = cost[s * 32 + col], s0 = sint[s * 32 + col];
                float c1 = cost[s * 32 + 16 + col], s1 = sint[s * 32 + 16 + col];
                dst[col] = (bf16)((v0 * c0 - v2 * s0) * sc);
                dst[16 + col] = (bf16)((v1 * c1 - v3 * s1) * sc);
                dst[32 + col] = (bf16)((v0 * s0 + v2 * c0) * sc);
                dst[48 + col] = (bf16)((v1 * s1 + v3 * c1) * sc);
            }
        }
    }
}

// ---------------------------------------------------------------------------
// Flash attention v12 = v8 interior (r7/r10 measured best, ~72us) + XCD
// L2-locality grid swap. v8's grid (qtile=8, bh=64) gave same-bh blocks
// consecutive IDs -> round-robin onto 8 DIFFERENT XCDs -> each XCD refetched
// the same 512KB K/V (FETCH 139MB vs ~64MB ideal). Grid (bh=64, qtile=8)
// makes same-bh IDs congruent mod 8 -> same XCD; per-XCD KV working set
// 8 bh x 512KB = 4MB = L2 size. Interior untouched (v9/v10/v11 each broke
// one of its three pillars: LDS economy, register budget, 2-ahead prefetch).
// ---------------------------------------------------------------------------
__global__ void __launch_bounds__(256, 2) attn_kernel(
    const bf16* __restrict__ Qw, const bf16* __restrict__ Kw,
    const bf16* __restrict__ Vt, bf16* __restrict__ X) {
    const int LDK = 72;
    const int LV = 36;
    __shared__ __attribute__((aligned(16))) bf16 lK[2][32 * LDK];
    __shared__ __attribute__((aligned(16))) bf16 lV[2][64 * LV];

    int t = threadIdx.x, lane = t & 63, w = t >> 6;
    int col = lane & 15, q = lane >> 4;
    int bh = blockIdx.x, b = bh >> 4, h = bh & 15;   // swapped: bh on x
    int q0 = blockIdx.y * 256 + w * 64;              // qtile on y
    const bf16* Qh = Qw + (size_t)bh * NS * NHD;
    const bf16* Kh = Kw + (size_t)bh * NS * NHD;
    const bf16* Vh = Vt + (size_t)bh * NHD * NS;

    int krow = t >> 3, kc = t & 7;
    int vrow = t >> 2, vc = t & 3;
    const bf16* gK = Kh + (size_t)krow * NHD + kc * 8;
    const bf16* gV = Vh + (size_t)vrow * NS + vc * 8;
    int wKoff = krow * LDK + kc * 8;
    int wVoff = vrow * LV + vc * 8;

    bf16x8 bQ[4][2];
#pragma unroll
    for (int mb = 0; mb < 4; ++mb)
#pragma unroll
        for (int h2 = 0; h2 < 2; ++h2)
            bQ[mb][h2] = *(const bf16x8*)(Qh + (size_t)(q0 + mb * 16 + col) * NHD + h2 * 32 + q * 8);

    f32x4 o[4][4];
#pragma unroll
    for (int mb = 0; mb < 4; ++mb)
#pragma unroll
        for (int hb = 0; hb < 4; ++hb) o[mb][hb] = (f32x4){0.f, 0.f, 0.f, 0.f};
    f32x4 dacc[4];
#pragma unroll
    for (int mb = 0; mb < 4; ++mb) dacc[mb] = (f32x4){0.f, 0.f, 0.f, 0.f};

    const bf16 one = (bf16)1.0f;
    bf16x8 ones = {one, one, one, one, one, one, one, one};

    bf16x8 kr[2], vr[2];
    kr[0] = *(const bf16x8*)gK;
    vr[0] = *(const bf16x8*)gV;
    kr[1] = *(const bf16x8*)(gK + (size_t)32 * NHD);
    vr[1] = *(const bf16x8*)(gV + 32);
    *(bf16x8*)&lK[0][wKoff] = kr[0];
    *(bf16x8*)&lV[0][wVoff] = vr[0];

#pragma unroll 2
    for (int it = 0; it < 64; ++it) {
        __syncthreads();
        int cur = it & 1, nxt = cur ^ 1;
        if (it + 2 < 64) {
            kr[cur] = *(const bf16x8*)(gK + (size_t)(it + 2) * 32 * NHD);
            vr[cur] = *(const bf16x8*)(gV + (it + 2) * 32);
        }

        bf16x8 aK[2][2];
#pragma unroll
        for (int tb = 0; tb < 2; ++tb)
#pragma unroll
            for (int h2 = 0; h2 < 2; ++h2)
                aK[tb][h2] = *(const bf16x8*)&lK[cur][(tb * 16 + col) * LDK + h2 * 32 + q * 8];
        bf16x8 vf[4];
#pragma unroll
        for (int hb = 0; hb < 4; ++hb) {
            const bf16* vp = &lV[cur][(hb * 16 + col) * LV + q * 4];
            bf16x4 lo = *(const bf16x4*)vp;
            bf16x4 hi = *(const bf16x4*)(vp + 16);
            vf[hb] = __builtin_shufflevector(lo, hi, 0, 1, 2, 3, 4, 5, 6, 7);
        }
        __builtin_amdgcn_s_setprio(1);
#pragma unroll
        for (int mb = 0; mb < 4; ++mb) {
            f32x4 s0 = (f32x4){0.f, 0.f, 0.f, 0.f};
            f32x4 s1 = (f32x4){0.f, 0.f, 0.f, 0.f};
            s0 = __builtin_amdgcn_mfma_f32_16x16x32_bf16(aK[0][0], bQ[mb][0], s0, 0, 0, 0);
            s0 = __builtin_amdgcn_mfma_f32_16x16x32_bf16(aK[0][1], bQ[mb][1], s0, 0, 0, 0);
            s1 = __builtin_amdgcn_mfma_f32_16x16x32_bf16(aK[1][0], bQ[mb][0], s1, 0, 0, 0);
            s1 = __builtin_amdgcn_mfma_f32_16x16x32_bf16(aK[1][1], bQ[mb][1], s1, 0, 0, 0);
            bf16x8 pf;
#pragma unroll
            for (int r = 0; r < 4; ++r) {
                float p0 = __builtin_amdgcn_exp2f(s0[r]);
                float p1 = __builtin_amdgcn_exp2f(s1[r]);
                pf[r] = (bf16)p0;
                pf[4 + r] = (bf16)p1;
            }
            dacc[mb] = __builtin_amdgcn_mfma_f32_16x16x32_bf16(ones, pf, dacc[mb], 0, 0, 0);
#pragma unroll
            for (int hb = 0; hb < 4; ++hb)
                o[mb][hb] = __builtin_amdgcn_mfma_f32_16x16x32_bf16(vf[hb], pf, o[mb][hb], 0, 0, 0);
        }
        __builtin_amdgcn_s_setprio(0);

        if (it + 1 < 64) {
            *(bf16x8*)&lK[nxt][wKoff] = kr[nxt];
            *(bf16x8*)&lV[nxt][wVoff] = vr[nxt];
        }
    }

#pragma unroll
    for (int mb = 0; mb < 4; ++mb) {
        float linv = 1.0f / dacc[mb][0];
        int s = q0 + mb * 16 + col;
        bf16* dst = X + (size_t)(b * NS + s) * ND + h * NHD;
#pragma unroll
        for (int hb = 0; hb < 4; ++hb) {
            bf16x4 ov = {(bf16)(o[mb][hb][0] * linv), (bf16)(o[mb][hb][1] * linv),
                         (bf16)(o[mb][hb][2] * linv), (bf16)(o[mb][hb][3] * linv)};
            *(bf16x4*)(dst + hb * 16 + q * 4) = ov;
        }
    }
}

// ---------------------------------------------------------------------------
// Output projection v5 (r7 measured best): BK=64 single-buffer swizzled loop.
// ---------------------------------------------------------------------------
__global__ void __launch_bounds__(256) out_gemm(
    const bf16* __restrict__ A, const bf16* __restrict__ W,
    const float* __restrict__ bias, float* __restrict__ out) {
    __shared__ __attribute__((aligned(16))) bf16 lA[128 * 64];
    __shared__ __attribute__((aligned(16))) bf16 lB[128 * 64];

    int t = threadIdx.x, lane = t & 63, w = t >> 6;
    int col = lane & 15, quad = lane >> 4;
    int m0 = blockIdx.y * 128, n0 = blockIdx.x * 128;
    int wm = (w >> 1) * 64, wn = (w & 1) * 64;

    f32x4 acc[4][4];
#pragma unroll
    for (int i = 0; i < 4; ++i)
#pragma unroll
        for (int j = 0; j < 4; ++j) acc[i][j] = (f32x4){0.f, 0.f, 0.f, 0.f};

    int srow = t >> 3;
    int sslot = (t & 7) ^ (srow & 7);
    const bf16* gA = A + (size_t)(m0 + srow) * ND + sslot * 8;
    const bf16* gB = W + (size_t)(n0 + srow) * ND + sslot * 8;
    int aRow = (wm + col) * 64;
    int bRow = (wn + col) * 64;

    for (int kt = 0; kt < 16; ++kt) {
        int kc = kt * 64;
#pragma unroll
        for (int c = 0; c < 4; ++c) {
            lds_dma16(gA + (size_t)(c * 32) * ND + kc, &lA[c * 2048 + t * 8]);
            lds_dma16(gB + (size_t)(c * 32) * ND + kc, &lB[c * 2048 + t * 8]);
        }
        __syncthreads();
#pragma unroll
        for (int kh = 0; kh < 2; ++kh) {
            int sk = ((kh * 4 + quad) ^ (col & 7)) * 8;
            bf16x8 af[4], bg[4];
#pragma unroll
            for (int i = 0; i < 4; ++i)
                af[i] = *(const bf16x8*)&lA[aRow + i * 1024 + sk];
#pragma unroll
            for (int j = 0; j < 4; ++j)
                bg[j] = *(const bf16x8*)&lB[bRow + j * 1024 + sk];
#pragma unroll
            for (int i = 0; i < 4; ++i)
#pragma unroll
                for (int j = 0; j < 4; ++j)
                    acc[i][j] = __builtin_amdgcn_mfma_f32_16x16x32_bf16(af[i], bg[j], acc[i][j], 0, 0, 0);
        }
        __syncthreads();
    }

    float bj[4];
#pragma unroll
    for (int j = 0; j < 4; ++j) bj[j] = bias[n0 + wn + j * 16 + col];
#pragma unroll
    for (int i = 0; i < 4; ++i)
#pragma unroll
        for (int r = 0; r < 4; ++r) {
            int m = m0 + wm + i * 16 + quad * 4 + r;
#pragma unroll
            for (int j = 0; j < 4; ++j)
                out[(size_t)m * ND + n0 + wn + j * 16 + col] = acc[i][j][r] + bj[j];
        }
}

// ---------------------------------------------------------------------------
// ws layout: cos|sin (512K) | Qw 16M | Kw 16M | Vt 16M | X 16M [| Wo_b 2M]
// ---------------------------------------------------------------------------
extern "C" void kernel_launch(void* const* d_in, const int* in_sizes, int n_in,
                              void* d_out, int out_size, void* d_ws, size_t ws_size,
                              hipStream_t stream) {
    const float* hs = (const float*)d_in[0];
    const float* Wqkv = (const float*)d_in[1];
    const float* bqkv = (const float*)d_in[2];
    const float* Wo = (const float*)d_in[3];
    const float* bo = (const float*)d_in[4];
    float* out = (float*)d_out;

    char* ws = (char*)d_ws;
    float* cost = (float*)ws;
    float* sint = cost + NS * 32;
    bf16* Qw = (bf16*)(ws + 524288);
    bf16* Kw = Qw + (size_t)NB * NH * NS * NHD;
    bf16* Vt = Kw + (size_t)NB * NH * NS * NHD;
    bf16* X = Vt + (size_t)NB * NH * NS * NHD;
    bf16* Wqkv_b = (bf16*)d_out;   // scratch inside d_out, dead before out_gemm

    const size_t base_end = 524288 + (size_t)4 * NB * NH * NS * NHD * 2;  // 64.5MB
    bool fuse_wo = ws_size >= base_end + (size_t)ND * ND * 2;
    bf16* Wo_b = fuse_wo ? (bf16*)(ws + base_end) : Qw;  // Qw dead after attn

    int prep_blocks = (NHS4 + NWQ4 + (fuse_wo ? NWO4 : 0)) / 256;
    prep_kernel<<<dim3(prep_blocks), dim3(256), 0, stream>>>(
        (const float4*)hs, (const float4*)Wqkv, (const float4*)Wo,
        cost, sint, (bf16x4*)X, (bf16x4*)Wqkv_b, (bf16x4*)Wo_b);
    qkv_rope_gemm<<<dim3(3 * ND / 128, NM / 128), dim3(256), 0, stream>>>(
        X, Wqkv_b, bqkv, cost, sint, Qw, Kw, Vt);
    attn_kernel<<<dim3(NB * NH, NS / 256), dim3(256), 0, stream>>>(Qw, Kw, Vt, X);
    if (!fuse_wo)
        cvt_bf16_kernel<<<dim3(ND * ND / 4 / 256), dim3(256), 0, stream>>>(
            (const float4*)Wo, (bf16x4*)Wo_b);
    out_gemm<<<dim3(ND / 128, NM / 128), dim3(256), 0, stream>>>(X, Wo_b, bo, out);
}